// Round 3
// baseline (1172.794 us; speedup 1.0000x reference)
//
#include <hip/hip_runtime.h>
#include <stdint.h>
#include <stddef.h>

// NASCell fused: new_m,new_c = gates(x@Wx, m_prev@Wm, c_prev)
// B=8192, I=H=1024, 8H=8192. Outputs fp32: new_m at [0,8.4M), new_c at [8.4M,16.8M).
//
// V4: V2's proven skeleton (LDS double-buffer + global_load_lds prefetch +
// barrier per kt) with 32x32x16 f16 MFMA and gate-PAIRED B fragments:
//  - one MFMA's N=32 = 2 gates x 16 h-cols -> MFMA instr count halves
//    (96 vs 192 per wave/kt) and pipe floor drops ~10% (2178 vs 1955 TF).
//  - acc: pairs {0,1},{4,5},{6,7} accumulate x+m in place (concat-K);
//    pair {2,3}: x-pass -> aX[1], m-pass -> aE (gate3 needs x*m split;
//    gate2's x+m is summed in the fp32 epilogue - same value).
//  - epilogue: lanes l and l^16 hold complementary gates for the same
//    (rows, h-col) -> one shfl_xor(16) per acc value unites them; each
//    lane stores its reg-half (no runtime indexing -> no scratch).
// prep_b emits B as 32 x 1KB lane-ordered fragment slabs per (hblk,kt) tile:
//   slab byte offset (((mat*4+pr)*2+ks)*2+hl)*1024, lane*16 within slab.
// k-mapping inside a fragment is safe by construction: A and B both pack
// 8 consecutive k at (lane>>5)*8 - any consistent k-bijection preserves
// the reduction. C/D: col=lane&31, row=(reg&3)+8*(reg>>2)+4*(lane>>5).

typedef _Float16 half8 __attribute__((ext_vector_type(8)));
typedef float f32x16 __attribute__((ext_vector_type(16)));
typedef float float4v __attribute__((ext_vector_type(4)));
typedef unsigned int u32;
typedef u32 u32x4 __attribute__((ext_vector_type(4)));
typedef float f32x4 __attribute__((ext_vector_type(4)));

__device__ __forceinline__ float fsig(float x) { return 1.0f / (1.0f + __expf(-x)); }
__device__ __forceinline__ float ftanh(float x) { return 2.0f * fsig(2.0f * x) - 1.0f; }
__device__ __forceinline__ u32 packh(_Float16 a, _Float16 b) {
  union { u32 u; _Float16 h[2]; } p;
  p.h[0] = a; p.h[1] = b; return p.u;
}

__device__ __forceinline__ void gload16(const void* g, void* l) {
  __builtin_amdgcn_global_load_lds(
      (const __attribute__((address_space(1))) void*)g,
      (__attribute__((address_space(3))) void*)l, 16, 0, 0);
}

// ---------------------------------------------------------------------------
// prep_b: per-(hblk,kt) 32KB tile = 32 slabs of 1KB, fragment-lane-ordered
// for 32x32x16. Slab (mat,pr,ks,hl); lane l in slab: col c=l&31 -> gate
// 2*pr+(c>>4), hcol c&15; k = kt*32 + ks*16 + (l>>5)*8 + j.
// Thread (mat,g,n): gathers col (g,n)'s 32 k values, scatters 8x16B chunks.
// ---------------------------------------------------------------------------
__global__ __launch_bounds__(256) void prep_b(
    const float* __restrict__ w_inputs, const float* __restrict__ w_m,
    char* __restrict__ wsB) {
  const int kt = blockIdx.x;    // 0..31
  const int hblk = blockIdx.y;  // 0..63
  const int tid = threadIdx.x;
  const int n = tid & 15;
  const int g = (tid >> 4) & 7;
  const int mat = tid >> 7;
  const int pr = g >> 1;
  const int hsel = g & 1;
  const int c = hsel * 16 + n;
  const float* w = mat ? w_m : w_inputs;
  const float* src = w + (size_t)kt * 32 * 8192 + (size_t)g * 1024 + hblk * 16 + n;
  _Float16 hs[32], ls[32];
#pragma unroll
  for (int k = 0; k < 32; ++k) {
    const float v = src[(size_t)k * 8192];
    const _Float16 h = (_Float16)v;
    hs[k] = h;
    ls[k] = (_Float16)(v - (float)h);
  }
  char* tile = wsB + ((size_t)hblk * 32 + kt) * 32768;
#pragma unroll
  for (int ks = 0; ks < 2; ++ks) {
#pragma unroll
    for (int lh = 0; lh < 2; ++lh) {
      const int lane = lh * 32 + c;
      const int kb = ks * 16 + lh * 8;
      u32x4 H = {packh(hs[kb + 0], hs[kb + 1]), packh(hs[kb + 2], hs[kb + 3]),
                 packh(hs[kb + 4], hs[kb + 5]), packh(hs[kb + 6], hs[kb + 7])};
      *(u32x4*)(tile + (size_t)((((mat * 4 + pr) * 2 + ks) * 2 + 0) * 1024 + lane * 16)) = H;
      u32x4 L = {packh(ls[kb + 0], ls[kb + 1]), packh(ls[kb + 2], ls[kb + 3]),
                 packh(ls[kb + 4], ls[kb + 5]), packh(ls[kb + 6], ls[kb + 7])};
      *(u32x4*)(tile + (size_t)((((mat * 4 + pr) * 2 + ks) * 2 + 1) * 1024 + lane * 16)) = L;
    }
  }
}

// ---------------------------------------------------------------------------
// split_ab: elementwise fp32 -> (hi fp16, lo fp16) for x (y=0) and m_prev (y=1).
// ---------------------------------------------------------------------------
__global__ __launch_bounds__(256) void split_ab(
    const float4v* __restrict__ xin, const float4v* __restrict__ min,
    half8* __restrict__ xhi, half8* __restrict__ xlo,
    half8* __restrict__ mhi, half8* __restrict__ mlo) {
  const int which = blockIdx.y;
  const float4v* in = which ? min : xin;
  half8* hi = which ? mhi : xhi;
  half8* lo = which ? mlo : xlo;
  const size_t idx = (size_t)blockIdx.x * 256 + threadIdx.x;
  const float4v a = in[idx * 2];
  const float4v b = in[idx * 2 + 1];
  half8 h, l;
#pragma unroll
  for (int j = 0; j < 4; ++j) {
    const float v = a[j]; const _Float16 hv = (_Float16)v;
    h[j] = hv; l[j] = (_Float16)(v - (float)hv);
  }
#pragma unroll
  for (int j = 0; j < 4; ++j) {
    const float v = b[j]; const _Float16 hv = (_Float16)v;
    h[4 + j] = hv; l[4 + j] = (_Float16)(v - (float)hv);
  }
  hi[idx] = h; lo[idx] = l;
}

// ---------------------------------------------------------------------------
// Main kernel V4: 256 rows x 16 h-cols per block, 4 waves x 64 rows (2 rg of
// 32), 32x32x16 f16 MFMA, gate-paired B. LDS 2x32KB double-buffer staged by
// global_load_lds, prefetch one kt ahead, barrier per kt.
// ---------------------------------------------------------------------------
__global__ __launch_bounds__(256, 2) void nascell_v4(
    const _Float16* __restrict__ xh_g, const _Float16* __restrict__ xl_g,
    const _Float16* __restrict__ mh_g, const _Float16* __restrict__ ml_g,
    const char* __restrict__ wsB,
    const float* __restrict__ c_prev,
    float* __restrict__ out) {
  __shared__ char lds[65536];  // 2 x 32KB
  const int tid = threadIdx.x;
  const int wid = tid >> 6;
  const int lane = tid & 63;
  const int row0 = blockIdx.y * 256;
  const int hblk = blockIdx.x;
  const int l31 = lane & 31;
  const int lh = lane >> 5;
  const int c16 = lane & 15;
  const int hsel = (lane >> 4) & 1;

  // A fragment bases: row = row0 + wid*64 + rg*32 + l31, k-offset lh*8.
  const _Float16* xhb[2]; const _Float16* xlb[2];
  const _Float16* mhb[2]; const _Float16* mlb[2];
#pragma unroll
  for (int rg = 0; rg < 2; ++rg) {
    const size_t arow = (size_t)(row0 + wid * 64 + rg * 32 + l31);
    xhb[rg] = xh_g + arow * 1024 + lh * 8;
    xlb[rg] = xl_g + arow * 1024 + lh * 8;
    mhb[rg] = mh_g + arow * 1024 + lh * 8;
    mlb[rg] = ml_g + arow * 1024 + lh * 8;
  }

  // staging: thread stages bytes tid*16 + r*4096 of each 32KB tile (linear).
  const char* wsb = wsB + (size_t)hblk * 32 * 32768 + tid * 16;
  char* ldsme = lds + tid * 16;

  f32x16 aX[2][4];  // [rg][pair] ; pairs {0,1},{2,3}(x-only),{4,5},{6,7}
  f32x16 aE[2];     // [rg] m-part of pair {2,3}
#pragma unroll
  for (int rg = 0; rg < 2; ++rg) {
#pragma unroll
    for (int p = 0; p < 4; ++p) aX[rg][p] = (f32x16)0.0f;
    aE[rg] = (f32x16)0.0f;
  }

  // prologue: stage tile kt=0 into buf0
#pragma unroll
  for (int r = 0; r < 8; ++r) gload16(wsb + r * 4096, ldsme + r * 4096);

  for (int kt = 0; kt < 32; ++kt) {
    __syncthreads();  // drains prefetch(kt); syncs waves

    // A fragment loads for kt (16 x 16B; oldest vmem => waits never drain prefetch)
    half8 axh[2][2], axl[2][2], amh[2][2], aml[2][2];
#pragma unroll
    for (int rg = 0; rg < 2; ++rg)
#pragma unroll
      for (int ks = 0; ks < 2; ++ks) {
        axh[rg][ks] = *(const half8*)(xhb[rg] + kt * 32 + ks * 16);
        axl[rg][ks] = *(const half8*)(xlb[rg] + kt * 32 + ks * 16);
        amh[rg][ks] = *(const half8*)(mhb[rg] + kt * 32 + ks * 16);
        aml[rg][ks] = *(const half8*)(mlb[rg] + kt * 32 + ks * 16);
      }
    __builtin_amdgcn_sched_barrier(0);
    if (kt < 31) {
      const char* src = wsb + (size_t)(kt + 1) * 32768;
      char* dst = lds + ((kt + 1) & 1) * 32768 + tid * 16;
#pragma unroll
      for (int r = 0; r < 8; ++r) gload16(src + r * 4096, dst + r * 4096);
    }
    __builtin_amdgcn_sched_barrier(0);

    const char* bb = lds + (kt & 1) * 32768 + (size_t)lane * 16;

    __builtin_amdgcn_s_setprio(1);
    // ---- x-pass (mat 0): aX[rg][pr] += xh*Bh + xh*Bl + xl*Bh ----
#pragma unroll
    for (int ks = 0; ks < 2; ++ks)
#pragma unroll
      for (int pr = 0; pr < 4; ++pr) {
        const half8 bh = *(const half8*)(bb + (size_t)(((pr * 2 + ks) * 2 + 0) * 1024));
        const half8 bl = *(const half8*)(bb + (size_t)(((pr * 2 + ks) * 2 + 1) * 1024));
#pragma unroll
        for (int rg = 0; rg < 2; ++rg) {
          f32x16 t = aX[rg][pr];
          t = __builtin_amdgcn_mfma_f32_32x32x16_f16(axh[rg][ks], bh, t, 0, 0, 0);
          t = __builtin_amdgcn_mfma_f32_32x32x16_f16(axh[rg][ks], bl, t, 0, 0, 0);
          t = __builtin_amdgcn_mfma_f32_32x32x16_f16(axl[rg][ks], bh, t, 0, 0, 0);
          aX[rg][pr] = t;
        }
      }
    // ---- m-pass (mat 1): pr!=1 in place; pr==1 -> aE ----
#pragma unroll
    for (int ks = 0; ks < 2; ++ks)
#pragma unroll
      for (int pr = 0; pr < 4; ++pr) {
        const half8 bh = *(const half8*)(bb + (size_t)((((4 + pr) * 2 + ks) * 2 + 0) * 1024));
        const half8 bl = *(const half8*)(bb + (size_t)((((4 + pr) * 2 + ks) * 2 + 1) * 1024));
#pragma unroll
        for (int rg = 0; rg < 2; ++rg) {
          f32x16 t = (pr == 1) ? aE[rg] : aX[rg][pr];
          t = __builtin_amdgcn_mfma_f32_32x32x16_f16(amh[rg][ks], bh, t, 0, 0, 0);
          t = __builtin_amdgcn_mfma_f32_32x32x16_f16(amh[rg][ks], bl, t, 0, 0, 0);
          t = __builtin_amdgcn_mfma_f32_32x32x16_f16(aml[rg][ks], bh, t, 0, 0, 0);
          if (pr == 1) aE[rg] = t; else aX[rg][pr] = t;
        }
      }
    __builtin_amdgcn_s_setprio(0);
  }

  // ---- epilogue: unite gate pairs via shfl_xor(16), combine, store ----
  float* out_m = out;
  float* out_c = out + (size_t)8192 * 1024;
  const int h = hblk * 16 + c16;
#pragma unroll
  for (int rg = 0; rg < 2; ++rg) {
#pragma unroll
    for (int reg = 0; reg < 16; ++reg) {
      const float o0 = aX[rg][0][reg], o1 = aX[rg][1][reg];
      const float o2 = aX[rg][2][reg], o3 = aX[rg][3][reg];
      const float oE = aE[rg][reg];
      const float r0 = __shfl_xor(o0, 16, 64);
      const float r1 = __shfl_xor(o1, 16, 64);
      const float r2 = __shfl_xor(o2, 16, 64);
      const float r3 = __shfl_xor(o3, 16, 64);
      const float rE = __shfl_xor(oE, 16, 64);
      const bool mine = (reg < 8) ? (hsel == 0) : (hsel == 1);
      if (mine) {
        // own = gate 2pr+hsel; received = gate 2pr+(1-hsel)
        const float p0 = hsel ? r0 : o0, p1 = hsel ? o0 : r0;
        const float x2 = hsel ? r1 : o1, x3 = hsel ? o1 : r1;
        const float m2 = hsel ? rE : oE, m3 = hsel ? oE : rE;
        const float p4 = hsel ? r2 : o2, p5 = hsel ? o2 : r2;
        const float p6 = hsel ? r3 : o3, p7 = hsel ? o3 : r3;
        const int grow = row0 + wid * 64 + rg * 32 + (reg & 3) + 8 * (reg >> 2) + 4 * lh;
        const float cp = c_prev[(size_t)grow * 1024 + h];
        float l1_0 = fsig(p0);
        float l1_1 = fmaxf(p1, 0.0f);
        float l1_2 = fsig(x2 + m2);
        float l1_3 = fmaxf(x3 * m3, 0.0f);
        float l1_4 = ftanh(p4);
        float l1_5 = fsig(p5);
        float l1_6 = ftanh(p6);
        float l1_7 = fsig(p7);
        float l2_0 = ftanh(l1_0 * l1_1);
        float l2_1 = ftanh(l1_2 + l1_3);
        float l2_2 = ftanh(l1_4 * l1_5);
        float l2_3 = fsig(l1_6 + l1_7);
        float l2_0b = ftanh(l2_0 + cp);
        float nc = l2_0b * l2_1;
        float l3_1 = ftanh(l2_2 + l2_3);
        float nm = ftanh(nc * l3_1);
        out_m[(size_t)grow * 1024 + h] = nm;
        out_c[(size_t)grow * 1024 + h] = nc;
      }
    }
  }
}

// ---------------------------------------------------------------------------
// Legacy kernel (V1) — fallback when ws_size < 128 MB. Unchanged.
// ---------------------------------------------------------------------------
__global__ __launch_bounds__(256, 2) void nascell_main(
    const float* __restrict__ x,
    const float* __restrict__ m_prev,
    const float* __restrict__ c_prev,
    const float* __restrict__ w_inputs,
    const float* __restrict__ w_m,
    float* __restrict__ out) {
  __shared__ short lds[17408];
  const int tid = threadIdx.x;
  const int wid = tid >> 6;
  const int lane = tid & 63;
  const int row0 = blockIdx.y * 256;
  const int h0 = blockIdx.x * 16;
  const int m16 = lane & 15;
  const int q = lane >> 4;

  const int bmat = tid >> 7;
  const int bg = (tid >> 4) & 7;
  const int bkp = (tid & 15) * 2;
  const float* wsrc = bmat ? w_m : w_inputs;
  const float* wrow_base = wsrc + (size_t)bkp * 8192 + (size_t)bg * 1024 + (size_t)h0;
  short* bh = lds + bmat * 4352 + bg * 544 + (bkp ^ ((bg & 3) << 3));
  short* bl = bh + 8704;

  const float* axp[4];
  const float* amp[4];
#pragma unroll
  for (int r = 0; r < 4; ++r) {
    const size_t arow = (size_t)(row0 + wid * 64 + r * 16 + m16);
    axp[r] = x + arow * 1024 + q * 8;
    amp[r] = m_prev + arow * 1024 + q * 8;
  }

  f32x4 acc[4][9];
#pragma unroll
  for (int r = 0; r < 4; ++r)
#pragma unroll
    for (int gg = 0; gg < 9; ++gg) acc[r][gg] = (f32x4)0.0f;

  for (int kt = 0; kt < 32; ++kt) {
    const float* wr = wrow_base + (size_t)kt * 32 * 8192;
    float4v b0 = *(const float4v*)(wr);
    float4v b1 = *(const float4v*)(wr + 4);
    float4v b2 = *(const float4v*)(wr + 8);
    float4v b3 = *(const float4v*)(wr + 12);
    float4v d0 = *(const float4v*)(wr + 8192);
    float4v d1 = *(const float4v*)(wr + 8196);
    float4v d2 = *(const float4v*)(wr + 8200);
    float4v d3 = *(const float4v*)(wr + 8204);

    float4v xa[4][2];
#pragma unroll
    for (int r = 0; r < 4; ++r) {
      xa[r][0] = *(const float4v*)(axp[r] + kt * 32);
      xa[r][1] = *(const float4v*)(axp[r] + kt * 32 + 4);
    }

    __syncthreads();

#pragma unroll
    for (int n = 0; n < 16; ++n) {
      const float r0 = (n < 4 ? b0[n & 3] : n < 8 ? b1[n & 3] : n < 12 ? b2[n & 3] : b3[n & 3]);
      const float r1 = (n < 4 ? d0[n & 3] : n < 8 ? d1[n & 3] : n < 12 ? d2[n & 3] : d3[n & 3]);
      const _Float16 h0v = (_Float16)r0;
      const _Float16 h1v = (_Float16)r1;
      *(u32*)(bh + n * 32) = packh(h0v, h1v);
      const _Float16 l0v = (_Float16)(r0 - (float)h0v);
      const _Float16 l1v = (_Float16)(r1 - (float)h1v);
      *(u32*)(bl + n * 32) = packh(l0v, l1v);
    }

    half8 axh[4], axl[4];
#pragma unroll
    for (int r = 0; r < 4; ++r)
#pragma unroll
      for (int j = 0; j < 8; ++j) {
        const float v = xa[r][j >> 2][j & 3];
        const _Float16 hv = (_Float16)v;
        axh[r][j] = hv;
        axl[r][j] = (_Float16)(v - (float)hv);
      }

    __syncthreads();

    float4v ma[4][2];
#pragma unroll
    for (int r = 0; r < 4; ++r) {
      ma[r][0] = *(const float4v*)(amp[r] + kt * 32);
      ma[r][1] = *(const float4v*)(amp[r] + kt * 32 + 4);
    }

#pragma unroll
    for (int c = 0; c < 8; ++c) {
      const int qs = (q ^ (c & 3)) * 8;
      const int bo = c * 544 + m16 * 32 + qs;
      half8 bxh = *(const half8*)(lds + bo);
      half8 bxl = *(const half8*)(lds + 8704 + bo);
#pragma unroll
      for (int r = 0; r < 4; ++r) {
        f32x4 t = acc[r][c];
        t = __builtin_amdgcn_mfma_f32_16x16x32_f16(axh[r], bxh, t, 0, 0, 0);
        t = __builtin_amdgcn_mfma_f32_16x16x32_f16(axh[r], bxl, t, 0, 0, 0);
        t = __builtin_amdgcn_mfma_f32_16x16x32_f16(axl[r], bxh, t, 0, 0, 0);
        acc[r][c] = t;
      }
    }

    half8 amh[4], aml[4];
#pragma unroll
    for (int r = 0; r < 4; ++r)
#pragma unroll
      for (int j = 0; j < 8; ++j) {
        const float v = ma[r][j >> 2][j & 3];
        const _Float16 hv = (_Float16)v;
        amh[r][j] = hv;
        aml[r][j] = (_Float16)(v - (float)hv);
      }

#pragma unroll
    for (int c = 0; c < 8; ++c) {
      const int qs = (q ^ (c & 3)) * 8;
      const int bo = 4352 + c * 544 + m16 * 32 + qs;
      half8 bmh = *(const half8*)(lds + bo);
      half8 bml = *(const half8*)(lds + 8704 + bo);
      const int tgt = (c == 3) ? 8 : c;
#pragma unroll
      for (int r = 0; r < 4; ++r) {
        f32x4 t = acc[r][tgt];
        t = __builtin_amdgcn_mfma_f32_16x16x32_f16(amh[r], bmh, t, 0, 0, 0);
        t = __builtin_amdgcn_mfma_f32_16x16x32_f16(amh[r], bml, t, 0, 0, 0);
        t = __builtin_amdgcn_mfma_f32_16x16x32_f16(aml[r], bmh, t, 0, 0, 0);
        acc[r][tgt] = t;
      }
    }
  }

  float* out_m = out;
  float* out_c = out + (size_t)8192 * 1024;
  const int h = h0 + m16;
#pragma unroll
  for (int r = 0; r < 4; ++r) {
#pragma unroll
    for (int i = 0; i < 4; ++i) {
      const int grow = row0 + wid * 64 + r * 16 + q * 4 + i;
      const float p0 = acc[r][0][i], p1 = acc[r][1][i], p2 = acc[r][2][i];
      const float x3 = acc[r][3][i], p4 = acc[r][4][i], p5 = acc[r][5][i];
      const float p6 = acc[r][6][i], p7 = acc[r][7][i], m3 = acc[r][8][i];
      const float cp = c_prev[(size_t)grow * 1024 + h];
      float l1_0 = fsig(p0);
      float l1_1 = fmaxf(p1, 0.0f);
      float l1_2 = fsig(p2);
      float l1_3 = fmaxf(x3 * m3, 0.0f);
      float l1_4 = ftanh(p4);
      float l1_5 = fsig(p5);
      float l1_6 = ftanh(p6);
      float l1_7 = fsig(p7);
      float l2_0 = ftanh(l1_0 * l1_1);
      float l2_1 = ftanh(l1_2 + l1_3);
      float l2_2 = ftanh(l1_4 * l1_5);
      float l2_3 = fsig(l1_6 + l1_7);
      float l2_0b = ftanh(l2_0 + cp);
      float nc = l2_0b * l2_1;
      float l3_1 = ftanh(l2_2 + l2_3);
      float nm = ftanh(nc * l3_1);
      out_m[(size_t)grow * 1024 + h] = nm;
      out_c[(size_t)grow * 1024 + h] = nc;
    }
  }
}

extern "C" void kernel_launch(void* const* d_in, const int* in_sizes, int n_in,
                              void* d_out, int out_size, void* d_ws, size_t ws_size,
                              hipStream_t stream) {
  (void)in_sizes; (void)n_in; (void)out_size;
  const float* x        = (const float*)d_in[0];
  const float* m_prev   = (const float*)d_in[1];
  const float* c_prev   = (const float*)d_in[2];
  const float* w_m      = (const float*)d_in[3];
  const float* w_inputs = (const float*)d_in[4];
  float* out = (float*)d_out;

  // ws layout: [0,64MB) B fragment tiles; then xh,xl,mh,ml (16MB each) = 128MB.
  if (ws_size >= 134217728ull && d_ws != nullptr) {
    char* wsB = (char*)d_ws;
    _Float16* xh = (_Float16*)((char*)d_ws + 67108864);
    _Float16* xl = xh + 8388608;
    _Float16* mh = xl + 8388608;
    _Float16* ml = mh + 8388608;
    prep_b<<<dim3(32, 64), 256, 0, stream>>>(w_inputs, w_m, wsB);
    split_ab<<<dim3(4096, 2), 256, 0, stream>>>(
        (const float4v*)x, (const float4v*)m_prev,
        (half8*)xh, (half8*)xl, (half8*)mh, (half8*)ml);
    nascell_v4<<<dim3(64, 32), 256, 0, stream>>>(xh, xl, mh, ml, wsB, c_prev, out);
  } else {
    dim3 grid(64, 32);
    nascell_main<<<grid, 256, 0, stream>>>(x, m_prev, c_prev, w_inputs, w_m, out);
  }
}

// Round 5
// 976.438 us; speedup vs baseline: 1.2011x; 1.2011x over previous
//
#include <hip/hip_runtime.h>
#include <stdint.h>
#include <stddef.h>

// NASCell fused: new_m,new_c = gates(x@Wx, m_prev@Wm, c_prev)
// B=8192, I=H=1024, 8H=8192. Outputs fp32: new_m at [0,8.4M), new_c at [8.4M,16.8M).
//
// V5 (resubmit; R4 was an infra failure, not a kernel result):
// V4's hardware-verified 32x32x16 math (prep_b tile images, gate-paired B,
// shfl_xor(16) epilogue) retiled for occupancy:
//  - 512-thread blocks, 8 waves, each wave = ONE 32-row group of the same
//    256 rows x 16 h-cols block tile. Grid unchanged (64,32).
//  - Per-wave regs: 5 x f32x16 accum (80) + A frags (16 live) + B (8) -> fits
//    the 128-VGPR budget of __launch_bounds__(512,4): 16 waves/CU, 4/SIMD —
//    2x V2's TLP, which is what the 45% latency bubble needs.
//  - m-frag loads issued between x-pass and m-pass (caps peak pressure).
//  - acc pairs {0,1},{4,5},{6,7} accumulate x+m in place (concat-K);
//    pair {2,3}: x-pass -> aX[1], m-pass -> aE; gate2's x+m summed in the
//    epilogue; gate3 uses split x3*m3 (exact same values as reference recipe).
// prep_b / split_ab byte-identical to V4 (verified correct on HW).
// LDS: 2 x 32KB double buffer staged by global_load_lds (16B), prefetch one
// kt ahead, one barrier per kt. B-fragment ds_read_b128 = lane*16 within 1KB
// slab -> conflict-free (measured 0).

typedef _Float16 half8 __attribute__((ext_vector_type(8)));
typedef float f32x16 __attribute__((ext_vector_type(16)));
typedef float float4v __attribute__((ext_vector_type(4)));
typedef unsigned int u32;
typedef u32 u32x4 __attribute__((ext_vector_type(4)));
typedef float f32x4 __attribute__((ext_vector_type(4)));

__device__ __forceinline__ float fsig(float x) { return 1.0f / (1.0f + __expf(-x)); }
__device__ __forceinline__ float ftanh(float x) { return 2.0f * fsig(2.0f * x) - 1.0f; }
__device__ __forceinline__ u32 packh(_Float16 a, _Float16 b) {
  union { u32 u; _Float16 h[2]; } p;
  p.h[0] = a; p.h[1] = b; return p.u;
}

__device__ __forceinline__ void gload16(const void* g, void* l) {
  __builtin_amdgcn_global_load_lds(
      (const __attribute__((address_space(1))) void*)g,
      (__attribute__((address_space(3))) void*)l, 16, 0, 0);
}

// ---------------------------------------------------------------------------
// prep_b: per-(hblk,kt) 32KB tile = 32 slabs of 1KB, fragment-lane-ordered
// for 32x32x16. Slab (mat,pr,ks,hl); lane l in slab: col c=l&31 -> gate
// 2*pr+(c>>4), hcol c&15; k = kt*32 + ks*16 + (l>>5)*8 + j.  [V4-verified]
// ---------------------------------------------------------------------------
__global__ __launch_bounds__(256) void prep_b(
    const float* __restrict__ w_inputs, const float* __restrict__ w_m,
    char* __restrict__ wsB) {
  const int kt = blockIdx.x;    // 0..31
  const int hblk = blockIdx.y;  // 0..63
  const int tid = threadIdx.x;
  const int n = tid & 15;
  const int g = (tid >> 4) & 7;
  const int mat = tid >> 7;
  const int pr = g >> 1;
  const int hsel = g & 1;
  const int c = hsel * 16 + n;
  const float* w = mat ? w_m : w_inputs;
  const float* src = w + (size_t)kt * 32 * 8192 + (size_t)g * 1024 + hblk * 16 + n;
  _Float16 hs[32], ls[32];
#pragma unroll
  for (int k = 0; k < 32; ++k) {
    const float v = src[(size_t)k * 8192];
    const _Float16 h = (_Float16)v;
    hs[k] = h;
    ls[k] = (_Float16)(v - (float)h);
  }
  char* tile = wsB + ((size_t)hblk * 32 + kt) * 32768;
#pragma unroll
  for (int ks = 0; ks < 2; ++ks) {
#pragma unroll
    for (int lh = 0; lh < 2; ++lh) {
      const int lane = lh * 32 + c;
      const int kb = ks * 16 + lh * 8;
      u32x4 H = {packh(hs[kb + 0], hs[kb + 1]), packh(hs[kb + 2], hs[kb + 3]),
                 packh(hs[kb + 4], hs[kb + 5]), packh(hs[kb + 6], hs[kb + 7])};
      *(u32x4*)(tile + (size_t)((((mat * 4 + pr) * 2 + ks) * 2 + 0) * 1024 + lane * 16)) = H;
      u32x4 L = {packh(ls[kb + 0], ls[kb + 1]), packh(ls[kb + 2], ls[kb + 3]),
                 packh(ls[kb + 4], ls[kb + 5]), packh(ls[kb + 6], ls[kb + 7])};
      *(u32x4*)(tile + (size_t)((((mat * 4 + pr) * 2 + ks) * 2 + 1) * 1024 + lane * 16)) = L;
    }
  }
}

// ---------------------------------------------------------------------------
// split_ab: elementwise fp32 -> (hi fp16, lo fp16) for x (y=0) and m_prev (y=1).
// ---------------------------------------------------------------------------
__global__ __launch_bounds__(256) void split_ab(
    const float4v* __restrict__ xin, const float4v* __restrict__ min,
    half8* __restrict__ xhi, half8* __restrict__ xlo,
    half8* __restrict__ mhi, half8* __restrict__ mlo) {
  const int which = blockIdx.y;
  const float4v* in = which ? min : xin;
  half8* hi = which ? mhi : xhi;
  half8* lo = which ? mlo : xlo;
  const size_t idx = (size_t)blockIdx.x * 256 + threadIdx.x;
  const float4v a = in[idx * 2];
  const float4v b = in[idx * 2 + 1];
  half8 h, l;
#pragma unroll
  for (int j = 0; j < 4; ++j) {
    const float v = a[j]; const _Float16 hv = (_Float16)v;
    h[j] = hv; l[j] = (_Float16)(v - (float)hv);
  }
#pragma unroll
  for (int j = 0; j < 4; ++j) {
    const float v = b[j]; const _Float16 hv = (_Float16)v;
    h[4 + j] = hv; l[4 + j] = (_Float16)(v - (float)hv);
  }
  hi[idx] = h; lo[idx] = l;
}

// ---------------------------------------------------------------------------
// Main kernel V5: 512 threads (8 waves x 32 rows), 256 rows x 16 h-cols per
// block, 32x32x16 f16 MFMA, gate-paired B. LDS 2x32KB double-buffer staged by
// global_load_lds, prefetch one kt ahead, one barrier per kt.
// ---------------------------------------------------------------------------
__global__ __launch_bounds__(512, 4) void nascell_v5(
    const _Float16* __restrict__ xh_g, const _Float16* __restrict__ xl_g,
    const _Float16* __restrict__ mh_g, const _Float16* __restrict__ ml_g,
    const char* __restrict__ wsB,
    const float* __restrict__ c_prev,
    float* __restrict__ out) {
  __shared__ char lds[65536];  // 2 x 32KB
  const int tid = threadIdx.x;
  const int wid = tid >> 6;    // 0..7, wave's 32-row group
  const int lane = tid & 63;
  const int row0 = blockIdx.y * 256;
  const int hblk = blockIdx.x;
  const int l31 = lane & 31;
  const int lh = lane >> 5;
  const int c16 = lane & 15;
  const int hsel = (lane >> 4) & 1;

  // A fragment bases: row = row0 + wid*32 + l31, k-offset lh*8 (+ks*16).
  const size_t arow = (size_t)(row0 + wid * 32 + l31);
  const _Float16* xhb = xh_g + arow * 1024 + lh * 8;
  const _Float16* xlb = xl_g + arow * 1024 + lh * 8;
  const _Float16* mhb = mh_g + arow * 1024 + lh * 8;
  const _Float16* mlb = ml_g + arow * 1024 + lh * 8;

  // staging: thread stages bytes tid*16 + r*8192 of each 32KB tile (linear).
  const char* wsb = wsB + (size_t)hblk * 32 * 32768 + tid * 16;
  char* ldsme = lds + tid * 16;

  f32x16 aX[4];  // pairs {0,1},{2,3}(x-only),{4,5},{6,7}
  f32x16 aE;     // m-part of pair {2,3}
#pragma unroll
  for (int p = 0; p < 4; ++p) aX[p] = (f32x16)0.0f;
  aE = (f32x16)0.0f;

  // prologue: stage tile kt=0 into buf0
#pragma unroll
  for (int r = 0; r < 4; ++r) gload16(wsb + r * 8192, ldsme + r * 8192);

  for (int kt = 0; kt < 32; ++kt) {
    __syncthreads();  // drains prefetch(kt); syncs waves

    // x fragment loads for kt (4 x 16B; oldest vmem)
    half8 axh[2], axl[2];
#pragma unroll
    for (int ks = 0; ks < 2; ++ks) {
      axh[ks] = *(const half8*)(xhb + kt * 32 + ks * 16);
      axl[ks] = *(const half8*)(xlb + kt * 32 + ks * 16);
    }
    __builtin_amdgcn_sched_barrier(0);
    if (kt < 31) {
      const char* src = wsb + (size_t)(kt + 1) * 32768;
      char* dst = lds + ((kt + 1) & 1) * 32768 + tid * 16;
#pragma unroll
      for (int r = 0; r < 4; ++r) gload16(src + r * 8192, dst + r * 8192);
    }
    __builtin_amdgcn_sched_barrier(0);

    const char* bb = lds + (kt & 1) * 32768 + (size_t)lane * 16;

    __builtin_amdgcn_s_setprio(1);
    // ---- x-pass (mat 0): aX[pr] += xh*Bh + xh*Bl + xl*Bh ----
#pragma unroll
    for (int ks = 0; ks < 2; ++ks)
#pragma unroll
      for (int pr = 0; pr < 4; ++pr) {
        const half8 bh = *(const half8*)(bb + (size_t)(((pr * 2 + ks) * 2 + 0) * 1024));
        const half8 bl = *(const half8*)(bb + (size_t)(((pr * 2 + ks) * 2 + 1) * 1024));
        f32x16 t = aX[pr];
        t = __builtin_amdgcn_mfma_f32_32x32x16_f16(axh[ks], bh, t, 0, 0, 0);
        t = __builtin_amdgcn_mfma_f32_32x32x16_f16(axh[ks], bl, t, 0, 0, 0);
        t = __builtin_amdgcn_mfma_f32_32x32x16_f16(axl[ks], bh, t, 0, 0, 0);
        aX[pr] = t;
      }
    __builtin_amdgcn_s_setprio(0);

    // m fragment loads (between passes: caps live registers at ~120)
    half8 amh[2], aml[2];
#pragma unroll
    for (int ks = 0; ks < 2; ++ks) {
      amh[ks] = *(const half8*)(mhb + kt * 32 + ks * 16);
      aml[ks] = *(const half8*)(mlb + kt * 32 + ks * 16);
    }

    __builtin_amdgcn_s_setprio(1);
    // ---- m-pass (mat 1): pr!=1 in place; pr==1 -> aE ----
#pragma unroll
    for (int ks = 0; ks < 2; ++ks)
#pragma unroll
      for (int pr = 0; pr < 4; ++pr) {
        const half8 bh = *(const half8*)(bb + (size_t)((((4 + pr) * 2 + ks) * 2 + 0) * 1024));
        const half8 bl = *(const half8*)(bb + (size_t)((((4 + pr) * 2 + ks) * 2 + 1) * 1024));
        f32x16 t = (pr == 1) ? aE : aX[pr];
        t = __builtin_amdgcn_mfma_f32_32x32x16_f16(amh[ks], bh, t, 0, 0, 0);
        t = __builtin_amdgcn_mfma_f32_32x32x16_f16(amh[ks], bl, t, 0, 0, 0);
        t = __builtin_amdgcn_mfma_f32_32x32x16_f16(aml[ks], bh, t, 0, 0, 0);
        if (pr == 1) aE = t; else aX[pr] = t;
      }
    __builtin_amdgcn_s_setprio(0);
  }

  // ---- epilogue: unite gate pairs via shfl_xor(16), combine, store ----
  // [V4-verified math; rows re-indexed for 1 rowgroup/wave]
  float* out_m = out;
  float* out_c = out + (size_t)8192 * 1024;
  const int h = hblk * 16 + c16;
#pragma unroll
  for (int reg = 0; reg < 16; ++reg) {
    const float o0 = aX[0][reg], o1 = aX[1][reg];
    const float o2 = aX[2][reg], o3 = aX[3][reg];
    const float oE = aE[reg];
    const float r0 = __shfl_xor(o0, 16, 64);
    const float r1 = __shfl_xor(o1, 16, 64);
    const float r2 = __shfl_xor(o2, 16, 64);
    const float r3 = __shfl_xor(o3, 16, 64);
    const float rE = __shfl_xor(oE, 16, 64);
    const bool mine = (reg < 8) ? (hsel == 0) : (hsel == 1);
    if (mine) {
      // own = gate 2pr+hsel; received = gate 2pr+(1-hsel)
      const float p0 = hsel ? r0 : o0, p1 = hsel ? o0 : r0;
      const float x2 = hsel ? r1 : o1, x3 = hsel ? o1 : r1;
      const float m2 = hsel ? rE : oE, m3 = hsel ? oE : rE;
      const float p4 = hsel ? r2 : o2, p5 = hsel ? o2 : r2;
      const float p6 = hsel ? r3 : o3, p7 = hsel ? o3 : r3;
      const int grow = row0 + wid * 32 + (reg & 3) + 8 * (reg >> 2) + 4 * lh;
      const float cp = c_prev[(size_t)grow * 1024 + h];
      float l1_0 = fsig(p0);
      float l1_1 = fmaxf(p1, 0.0f);
      float l1_2 = fsig(x2 + m2);
      float l1_3 = fmaxf(x3 * m3, 0.0f);
      float l1_4 = ftanh(p4);
      float l1_5 = fsig(p5);
      float l1_6 = ftanh(p6);
      float l1_7 = fsig(p7);
      float l2_0 = ftanh(l1_0 * l1_1);
      float l2_1 = ftanh(l1_2 + l1_3);
      float l2_2 = ftanh(l1_4 * l1_5);
      float l2_3 = fsig(l1_6 + l1_7);
      float l2_0b = ftanh(l2_0 + cp);
      float nc = l2_0b * l2_1;
      float l3_1 = ftanh(l2_2 + l2_3);
      float nm = ftanh(nc * l3_1);
      out_m[(size_t)grow * 1024 + h] = nm;
      out_c[(size_t)grow * 1024 + h] = nc;
    }
  }
}

// ---------------------------------------------------------------------------
// Legacy kernel (V1) — fallback when ws_size < 128 MB. Unchanged.
// ---------------------------------------------------------------------------
__global__ __launch_bounds__(256, 2) void nascell_main(
    const float* __restrict__ x,
    const float* __restrict__ m_prev,
    const float* __restrict__ c_prev,
    const float* __restrict__ w_inputs,
    const float* __restrict__ w_m,
    float* __restrict__ out) {
  __shared__ short lds[17408];
  const int tid = threadIdx.x;
  const int wid = tid >> 6;
  const int lane = tid & 63;
  const int row0 = blockIdx.y * 256;
  const int h0 = blockIdx.x * 16;
  const int m16 = lane & 15;
  const int q = lane >> 4;

  const int bmat = tid >> 7;
  const int bg = (tid >> 4) & 7;
  const int bkp = (tid & 15) * 2;
  const float* wsrc = bmat ? w_m : w_inputs;
  const float* wrow_base = wsrc + (size_t)bkp * 8192 + (size_t)bg * 1024 + (size_t)h0;
  short* bh = lds + bmat * 4352 + bg * 544 + (bkp ^ ((bg & 3) << 3));
  short* bl = bh + 8704;

  const float* axp[4];
  const float* amp[4];
#pragma unroll
  for (int r = 0; r < 4; ++r) {
    const size_t arow = (size_t)(row0 + wid * 64 + r * 16 + m16);
    axp[r] = x + arow * 1024 + q * 8;
    amp[r] = m_prev + arow * 1024 + q * 8;
  }

  f32x4 acc[4][9];
#pragma unroll
  for (int r = 0; r < 4; ++r)
#pragma unroll
    for (int gg = 0; gg < 9; ++gg) acc[r][gg] = (f32x4)0.0f;

  for (int kt = 0; kt < 32; ++kt) {
    const float* wr = wrow_base + (size_t)kt * 32 * 8192;
    float4v b0 = *(const float4v*)(wr);
    float4v b1 = *(const float4v*)(wr + 4);
    float4v b2 = *(const float4v*)(wr + 8);
    float4v b3 = *(const float4v*)(wr + 12);
    float4v d0 = *(const float4v*)(wr + 8192);
    float4v d1 = *(const float4v*)(wr + 8196);
    float4v d2 = *(const float4v*)(wr + 8200);
    float4v d3 = *(const float4v*)(wr + 8204);

    float4v xa[4][2];
#pragma unroll
    for (int r = 0; r < 4; ++r) {
      xa[r][0] = *(const float4v*)(axp[r] + kt * 32);
      xa[r][1] = *(const float4v*)(axp[r] + kt * 32 + 4);
    }

    __syncthreads();

#pragma unroll
    for (int n = 0; n < 16; ++n) {
      const float r0 = (n < 4 ? b0[n & 3] : n < 8 ? b1[n & 3] : n < 12 ? b2[n & 3] : b3[n & 3]);
      const float r1 = (n < 4 ? d0[n & 3] : n < 8 ? d1[n & 3] : n < 12 ? d2[n & 3] : d3[n & 3]);
      const _Float16 h0v = (_Float16)r0;
      const _Float16 h1v = (_Float16)r1;
      *(u32*)(bh + n * 32) = packh(h0v, h1v);
      const _Float16 l0v = (_Float16)(r0 - (float)h0v);
      const _Float16 l1v = (_Float16)(r1 - (float)h1v);
      *(u32*)(bl + n * 32) = packh(l0v, l1v);
    }

    half8 axh[4], axl[4];
#pragma unroll
    for (int r = 0; r < 4; ++r)
#pragma unroll
      for (int j = 0; j < 8; ++j) {
        const float v = xa[r][j >> 2][j & 3];
        const _Float16 hv = (_Float16)v;
        axh[r][j] = hv;
        axl[r][j] = (_Float16)(v - (float)hv);
      }

    __syncthreads();

    float4v ma[4][2];
#pragma unroll
    for (int r = 0; r < 4; ++r) {
      ma[r][0] = *(const float4v*)(amp[r] + kt * 32);
      ma[r][1] = *(const float4v*)(amp[r] + kt * 32 + 4);
    }

#pragma unroll
    for (int c = 0; c < 8; ++c) {
      const int qs = (q ^ (c & 3)) * 8;
      const int bo = c * 544 + m16 * 32 + qs;
      half8 bxh = *(const half8*)(lds + bo);
      half8 bxl = *(const half8*)(lds + 8704 + bo);
#pragma unroll
      for (int r = 0; r < 4; ++r) {
        f32x4 t = acc[r][c];
        t = __builtin_amdgcn_mfma_f32_16x16x32_f16(axh[r], bxh, t, 0, 0, 0);
        t = __builtin_amdgcn_mfma_f32_16x16x32_f16(axh[r], bxl, t, 0, 0, 0);
        t = __builtin_amdgcn_mfma_f32_16x16x32_f16(axl[r], bxh, t, 0, 0, 0);
        acc[r][c] = t;
      }
    }

    half8 amh[4], aml[4];
#pragma unroll
    for (int r = 0; r < 4; ++r)
#pragma unroll
      for (int j = 0; j < 8; ++j) {
        const float v = ma[r][j >> 2][j & 3];
        const _Float16 hv = (_Float16)v;
        amh[r][j] = hv;
        aml[r][j] = (_Float16)(v - (float)hv);
      }

#pragma unroll
    for (int c = 0; c < 8; ++c) {
      const int qs = (q ^ (c & 3)) * 8;
      const int bo = 4352 + c * 544 + m16 * 32 + qs;
      half8 bmh = *(const half8*)(lds + bo);
      half8 bml = *(const half8*)(lds + 8704 + bo);
      const int tgt = (c == 3) ? 8 : c;
#pragma unroll
      for (int r = 0; r < 4; ++r) {
        f32x4 t = acc[r][tgt];
        t = __builtin_amdgcn_mfma_f32_16x16x32_f16(amh[r], bmh, t, 0, 0, 0);
        t = __builtin_amdgcn_mfma_f32_16x16x32_f16(amh[r], bml, t, 0, 0, 0);
        t = __builtin_amdgcn_mfma_f32_16x16x32_f16(aml[r], bmh, t, 0, 0, 0);
        acc[r][tgt] = t;
      }
    }
  }

  float* out_m = out;
  float* out_c = out + (size_t)8192 * 1024;
  const int h = h0 + m16;
#pragma unroll
  for (int r = 0; r < 4; ++r) {
#pragma unroll
    for (int i = 0; i < 4; ++i) {
      const int grow = row0 + wid * 64 + r * 16 + q * 4 + i;
      const float p0 = acc[r][0][i], p1 = acc[r][1][i], p2 = acc[r][2][i];
      const float x3 = acc[r][3][i], p4 = acc[r][4][i], p5 = acc[r][5][i];
      const float p6 = acc[r][6][i], p7 = acc[r][7][i], m3 = acc[r][8][i];
      const float cp = c_prev[(size_t)grow * 1024 + h];
      float l1_0 = fsig(p0);
      float l1_1 = fmaxf(p1, 0.0f);
      float l1_2 = fsig(p2);
      float l1_3 = fmaxf(x3 * m3, 0.0f);
      float l1_4 = ftanh(p4);
      float l1_5 = fsig(p5);
      float l1_6 = ftanh(p6);
      float l1_7 = fsig(p7);
      float l2_0 = ftanh(l1_0 * l1_1);
      float l2_1 = ftanh(l1_2 + l1_3);
      float l2_2 = ftanh(l1_4 * l1_5);
      float l2_3 = fsig(l1_6 + l1_7);
      float l2_0b = ftanh(l2_0 + cp);
      float nc = l2_0b * l2_1;
      float l3_1 = ftanh(l2_2 + l2_3);
      float nm = ftanh(nc * l3_1);
      out_m[(size_t)grow * 1024 + h] = nm;
      out_c[(size_t)grow * 1024 + h] = nc;
    }
  }
}

extern "C" void kernel_launch(void* const* d_in, const int* in_sizes, int n_in,
                              void* d_out, int out_size, void* d_ws, size_t ws_size,
                              hipStream_t stream) {
  (void)in_sizes; (void)n_in; (void)out_size;
  const float* x        = (const float*)d_in[0];
  const float* m_prev   = (const float*)d_in[1];
  const float* c_prev   = (const float*)d_in[2];
  const float* w_m      = (const float*)d_in[3];
  const float* w_inputs = (const float*)d_in[4];
  float* out = (float*)d_out;

  // ws layout: [0,64MB) B fragment tiles; then xh,xl,mh,ml (16MB each) = 128MB.
  if (ws_size >= 134217728ull && d_ws != nullptr) {
    char* wsB = (char*)d_ws;
    _Float16* xh = (_Float16*)((char*)d_ws + 67108864);
    _Float16* xl = xh + 8388608;
    _Float16* mh = xl + 8388608;
    _Float16* ml = mh + 8388608;
    prep_b<<<dim3(32, 64), 256, 0, stream>>>(w_inputs, w_m, wsB);
    split_ab<<<dim3(4096, 2), 256, 0, stream>>>(
        (const float4v*)x, (const float4v*)m_prev,
        (half8*)xh, (half8*)xl, (half8*)mh, (half8*)ml);
    nascell_v5<<<dim3(64, 32), 512, 0, stream>>>(xh, xl, mh, ml, wsB, c_prev, out);
  } else {
    dim3 grid(64, 32);
    nascell_main<<<grid, 256, 0, stream>>>(x, m_prev, c_prev, w_inputs, w_m, out);
  }
}